// Round 4
// baseline (138.381 us; speedup 1.0000x reference)
//
#include <hip/hip_runtime.h>

#define B 128
#define N 1024
#define L 512
#define D 64

typedef float f32x4 __attribute__((ext_vector_type(4)));
typedef short bf16x8 __attribute__((ext_vector_type(8)));

// RNE fp32 -> bf16, packed pair into one uint
__device__ inline unsigned int pack_bf16(float lo, float hi) {
    unsigned int a = __float_as_uint(lo), b = __float_as_uint(hi);
    a = (a + 0x7fffu + ((a >> 16) & 1u)) >> 16;
    b = (b + 0x7fffu + ((b >> 16) & 1u)) & 0xffff0000u;
    return a | b;
}

// ws layout: float sims[3*B]
//
// grid = 3*B blocks x 256 threads. Block (s,b): stage full image Ib as bf16 in
// MFMA-fragment order in LDS (64 KB, conflict-free reads), loop token chunks.
// Fragment order: 16-byte chunk ci = g*64 + ln  (g = rt*2 + h) holds
//   region = rt*16 + (ln&15), d-range = h*32 + (ln>>4)*8 .. +8
// Byte offset of chunk = ci*16; group g starts at BYTE g*1024 (bug in R3: the
// read used short units -> 2x stride -> OOB LDS -> inf).
// redT/redI/wsum alias the front of ldsI (phases separated by barriers) so
// static LDS is exactly 65536 B.
__global__ __launch_bounds__(256, 2) void sim_kernel(
        const float* __restrict__ T, const float* __restrict__ I,
        const float* __restrict__ tmask, const float* __restrict__ imask,
        const int* __restrict__ Iimp, const int* __restrict__ Simp,
        float* __restrict__ sims) {
    int blk = blockIdx.x;          // 0..383
    int s = blk >> 7;              // 0..2
    int b = blk & (B - 1);
    int Tb = b, Ib = b;
    if (s == 1) Tb = Simp[b];
    else if (s == 2) Ib = Iimp[b];

    int tid = threadIdx.x;
    int w = tid >> 6;
    int lane = tid & 63;
    int q = lane >> 4;
    int c = lane & 15;

    __shared__ unsigned short ldsI[L * D];   // exactly 64 KB
    float* redf = (float*)ldsI;              // [0..3]=redT [4..7]=redI [8..11]=wsum

    // ---- phase 1: mask sums (prefix masks -> counts) ----
    float ts = 0.f, is = 0.f;
    {
        const float* tm = tmask + (size_t)Tb * N;
        for (int i = tid; i < N; i += 256) ts += tm[i];
        const float* im = imask + (size_t)Ib * L;
        for (int i = tid; i < L; i += 256) is += im[i];
    }
    for (int off = 32; off > 0; off >>= 1) {
        ts += __shfl_down(ts, off);
        is += __shfl_down(is, off);
    }
    if (lane == 0) { redf[w] = ts; redf[4 + w] = is; }
    __syncthreads();
    int ntok = (int)(redf[0] + redf[1] + redf[2] + redf[3] + 0.5f);
    int nreg = (int)(redf[4] + redf[5] + redf[6] + redf[7] + 0.5f);
    __syncthreads();   // counts read by all before staging overwrites redf

    // ---- phase 2: stage image Ib (bf16, fragment order) ----
    int full_rt = nreg >> 4;
    int rem = nreg & 15;
    int nrt = full_rt + (rem ? 1 : 0);
    int nchunk = nrt * 128;                  // 16B chunks
    const float* Ibase = I + (size_t)Ib * L * D;
    for (int ci = tid; ci < nchunk; ci += 256) {
        int rt = ci >> 7;
        int h = (ci >> 6) & 1;
        int ln = ci & 63;
        int r = rt * 16 + (ln & 15);
        int dbase = h * 32 + (ln >> 4) * 8;
        uint4 outv = make_uint4(0u, 0u, 0u, 0u);
        if (r < nreg) {
            const float4* p = (const float4*)(Ibase + (size_t)r * D + dbase);
            float4 f0 = p[0], f1 = p[1];
            outv.x = pack_bf16(f0.x, f0.y);
            outv.y = pack_bf16(f0.z, f0.w);
            outv.z = pack_bf16(f1.x, f1.y);
            outv.w = pack_bf16(f1.z, f1.w);
        }
        *(uint4*)((char*)ldsI + (size_t)ci * 16) = outv;
    }
    __syncthreads();

    // ---- phase 3: token-chunk loop (256 tokens per chunk, 64 per wave) ----
    const char* ldsB = (const char*)ldsI + (size_t)lane * 16;  // BYTE arithmetic
    float bsum = 0.f;
    for (int tok0 = 0; tok0 < ntok; tok0 += 256) {
        int wt0 = tok0 + w * 64;
        // A fragments: 4 token tiles x 2 K-halves (rows always < N: safe reads)
        bf16x8 afrag[4][2];
#pragma unroll
        for (int tt = 0; tt < 4; ++tt) {
            const float* trow = T + ((size_t)Tb * N + wt0 + tt * 16 + c) * D;
#pragma unroll
            for (int h = 0; h < 2; ++h) {
                const float4* p = (const float4*)(trow + h * 32 + q * 8);
                float4 f0 = p[0], f1 = p[1];
                unsigned int u[4];
                u[0] = pack_bf16(f0.x, f0.y);
                u[1] = pack_bf16(f0.z, f0.w);
                u[2] = pack_bf16(f1.x, f1.y);
                u[3] = pack_bf16(f1.z, f1.w);
                afrag[tt][h] = *(bf16x8*)u;
            }
        }

        float mx[4][4];
#pragma unroll
        for (int tt = 0; tt < 4; ++tt)
#pragma unroll
            for (int i = 0; i < 4; ++i) mx[tt][i] = -3.0e38f;

        // full region tiles: unpredicated max
#pragma unroll 1
        for (int rt = 0; rt < full_rt; ++rt) {
            bf16x8 b0 = *(const bf16x8*)(ldsB + (size_t)(rt * 2 + 0) * 1024);
            bf16x8 b1 = *(const bf16x8*)(ldsB + (size_t)(rt * 2 + 1) * 1024);
#pragma unroll
            for (int tt = 0; tt < 4; ++tt) {
                f32x4 acc = {0.f, 0.f, 0.f, 0.f};
                acc = __builtin_amdgcn_mfma_f32_16x16x32_bf16(afrag[tt][0], b0, acc, 0, 0, 0);
                acc = __builtin_amdgcn_mfma_f32_16x16x32_bf16(afrag[tt][1], b1, acc, 0, 0, 0);
#pragma unroll
                for (int i = 0; i < 4; ++i) mx[tt][i] = fmaxf(mx[tt][i], acc[i]);
            }
        }
        // partial tile: predicate on region validity (zero-padded staging)
        if (rem) {
            bf16x8 b0 = *(const bf16x8*)(ldsB + (size_t)(full_rt * 2 + 0) * 1024);
            bf16x8 b1 = *(const bf16x8*)(ldsB + (size_t)(full_rt * 2 + 1) * 1024);
            bool valid = c < rem;
#pragma unroll
            for (int tt = 0; tt < 4; ++tt) {
                f32x4 acc = {0.f, 0.f, 0.f, 0.f};
                acc = __builtin_amdgcn_mfma_f32_16x16x32_bf16(afrag[tt][0], b0, acc, 0, 0, 0);
                acc = __builtin_amdgcn_mfma_f32_16x16x32_bf16(afrag[tt][1], b1, acc, 0, 0, 0);
                if (valid) {
#pragma unroll
                    for (int i = 0; i < 4; ++i) mx[tt][i] = fmaxf(mx[tt][i], acc[i]);
                }
            }
        }

        // cross-lane max over the 16 cols
#pragma unroll
        for (int m = 1; m < 16; m <<= 1) {
#pragma unroll
            for (int tt = 0; tt < 4; ++tt)
#pragma unroll
                for (int i = 0; i < 4; ++i)
                    mx[tt][i] = fmaxf(mx[tt][i], __shfl_xor(mx[tt][i], m));
        }
        // masked token sum (C layout: row = q*4 + i within tile)
        if (c == 0) {
#pragma unroll
            for (int tt = 0; tt < 4; ++tt)
#pragma unroll
                for (int i = 0; i < 4; ++i) {
                    int row = wt0 + tt * 16 + q * 4 + i;
                    if (row < ntok) bsum += mx[tt][i];
                }
        }
    }

    // ---- phase 4: block reduce + store (redf[8..11] reused AFTER a barrier) ----
    for (int off = 32; off > 0; off >>= 1) bsum += __shfl_down(bsum, off);
    __syncthreads();   // all waves done reading ldsI before we overwrite chunk 0
    if (lane == 0) redf[8 + w] = bsum;
    __syncthreads();
    if (tid == 0)
        sims[s * B + b] = (redf[8] + redf[9] + redf[10] + redf[11]) / (float)ntok;
}

__global__ void loss_kernel(const float* __restrict__ sims,
                            float* __restrict__ out) {
    int tid = threadIdx.x;  // 128 threads
    float anc = sims[tid];
    float simp = sims[B + tid];
    float iimp = sims[2 * B + tid];
    float per = fmaxf(1.f + iimp - anc, 0.f) + fmaxf(1.f + simp - anc, 0.f);
    for (int off = 32; off > 0; off >>= 1) per += __shfl_down(per, off);
    __shared__ float w2[2];
    if ((tid & 63) == 0) w2[tid >> 6] = per;
    __syncthreads();
    if (tid == 0) out[0] = (w2[0] + w2[1]) / (float)B;
}

extern "C" void kernel_launch(void* const* d_in, const int* in_sizes, int n_in,
                              void* d_out, int out_size, void* d_ws, size_t ws_size,
                              hipStream_t stream) {
    const float* T     = (const float*)d_in[0];
    const float* I     = (const float*)d_in[1];
    const float* tmask = (const float*)d_in[2];
    const float* imask = (const float*)d_in[3];
    const int*   Iimp  = (const int*)d_in[4];
    const int*   Simp  = (const int*)d_in[5];
    float* sims = (float*)d_ws;

    sim_kernel<<<3 * B, 256, 0, stream>>>(T, I, tmask, imask, Iimp, Simp, sims);
    loss_kernel<<<1, 128, 0, stream>>>(sims, (float*)d_out);
}